// Round 9
// baseline (405.912 us; speedup 1.0000x reference)
//
#include <hip/hip_runtime.h>

typedef __bf16 bf16_t;
typedef __bf16 bf16x8 __attribute__((ext_vector_type(8)));
typedef __bf16 bf16x4 __attribute__((ext_vector_type(4)));
typedef float f32x4 __attribute__((ext_vector_type(4)));
typedef unsigned int u32x4 __attribute__((ext_vector_type(4)));

static constexpr int Bq = 4, Gg = 8, Nn = 128, Tt = 6000, Hh = 384;
static constexpr int TB = 16;              // t-values per tile
static constexpr int NTPB = Tt / TB;       // 375 tiles per batch
static constexpr int NTILES = Bq * NTPB;   // 1500 tiles (128 rows each)
static constexpr int LDA = 136;            // As row stride (bf16)
static constexpr int LDSM = 392;           // Sm/Mm row stride (bf16)
static constexpr int LDV = 132;            // Vv row stride (f32)

// workspace layout (bytes)
static constexpr size_t OFF_WI  = 0;                                    // 384x128 bf16
static constexpr size_t OFF_WM  = OFF_WI + (size_t)Hh * Nn * 2;         // 384x384 bf16
static constexpr size_t OFF_WO  = OFF_WM + (size_t)Hh * Hh * 2;         // 128x768 bf16
static constexpr size_t OFF_PT  = OFF_WO + (size_t)Nn * 2 * Hh * 2;     // part[1500][16] f32
static constexpr size_t OFF_MRS = OFF_PT + (size_t)NTILES * 16 * 4;     // 32x2 f32
static constexpr size_t OFF_GO  = (size_t)2 << 20;                      // go bf16
static constexpr size_t WS_NEED = OFF_GO + (size_t)Bq * Tt * Gg * Nn * 2; // ~51.2 MB

// k1 LDS layout (bytes). As dead after per-wave frag loads -> Mm/Vv reuse it.
static constexpr int SM_AS = 0;            // As [128][136] bf16 = 34816
static constexpr int SM_MM = 0;            // Mm [16][392] bf16 = 12544 (reuses As)
static constexpr int SM_VV = 12544;        // Vv [16][132] f32 = 8448 (reuses As, ends 20992)
static constexpr int SM_SM = 34816;        // Sm [16][392] bf16 -> 47360
static constexpr int SM_BI = 47360;        // bi f32[384] -> 48896
static constexpr int SM_BM = 48896;        // bm f32[384] -> 50432
static constexpr int SM_BO = 50432;        // bo f32[128] -> 50944
static constexpr int SM_ST = 50944;        // st f32[16]  -> 51008
static constexpr int SMEM_BYTES = 51008;   // <=80KB -> 2 blocks/CU (16 waves)

#define MFMA16(a, b, c) __builtin_amdgcn_mfma_f32_16x16x32_bf16((a), (b), (c), 0, 0, 0)

__global__ void k0_prep(const float* __restrict__ Wi, const float* __restrict__ Wm,
                        const float* __restrict__ Wo,
                        bf16_t* __restrict__ WiB, bf16_t* __restrict__ WmB,
                        bf16_t* __restrict__ WoB) {
    int i = blockIdx.x * blockDim.x + threadIdx.x;
    const int n1 = Hh * Nn, n2 = Hh * Hh, n3 = Nn * 2 * Hh;
    for (int idx = i; idx < n1 + n2 + n3; idx += gridDim.x * blockDim.x) {
        if (idx < n1)            WiB[idx] = (bf16_t)Wi[idx];
        else if (idx < n1 + n2)  WmB[idx - n1] = (bf16_t)Wm[idx - n1];
        else                     WoB[idx - n1 - n2] = (bf16_t)Wo[idx - n1 - n2];
    }
}

// As column swizzle at 16B granularity: granule (c>>3) XOR tl, tl=(row>>3)&7.
__device__ __forceinline__ int as_col(int row, int c) {
    return ((((c >> 3) ^ ((row >> 3) & 7)) << 3) | (c & 7));
}

__device__ __forceinline__ unsigned int pk2(float a, float b) {
    unsigned short lo = __builtin_bit_cast(unsigned short, (bf16_t)a);
    unsigned short hi = __builtin_bit_cast(unsigned short, (bf16_t)b);
    return (unsigned int)lo | ((unsigned int)hi << 16);
}

__global__ __launch_bounds__(512, 4)
void k1_fused(const float* __restrict__ x,
              const bf16_t* __restrict__ WiB, const float* __restrict__ bi, const float* __restrict__ aip,
              const bf16_t* __restrict__ WmB, const float* __restrict__ bm, const float* __restrict__ amp,
              const bf16_t* __restrict__ WoB, const float* __restrict__ bo, const float* __restrict__ aop,
              bf16_t* __restrict__ go, float* __restrict__ part) {
    __shared__ char smem[SMEM_BYTES];
    bf16_t* As  = (bf16_t*)(smem + SM_AS);
    bf16_t* Mm  = (bf16_t*)(smem + SM_MM);
    float*  Vv  = (float*)(smem + SM_VV);
    bf16_t* Sm  = (bf16_t*)(smem + SM_SM);
    float*  sbi = (float*)(smem + SM_BI);
    float*  sbm = (float*)(smem + SM_BM);
    float*  sbo = (float*)(smem + SM_BO);
    float*  st  = (float*)(smem + SM_ST);

    const int tid  = threadIdx.x;
    const int lane = tid & 63;
    const int w    = tid >> 6;       // wave 0..7: owns output rows w*16..w*16+15
    const int l15  = lane & 15;
    const int l4   = lane >> 4;      // 0..3
    const int tile = blockIdx.x;
    const int b    = tile / NTPB, t0 = (tile % NTPB) * TB;

    if (tid < 384) { sbi[tid] = bi[tid]; sbm[tid] = bm[tid]; }
    if (tid >= 384 && tid < 512) sbo[tid - 384] = bo[tid - 384];
    if (tid < 16) st[tid] = 0.f;

    // ---- stage x[b, g, n, t0:t0+16] -> As[tl*8+g][swz(n)] (block-cooperative, coalesced)
    {
        const int g0 = tid >> 7, n0 = tid & 127;
        #pragma unroll
        for (int h = 0; h < 2; h++) {
            int gg = g0 + 4 * h;
            #pragma unroll
            for (int q = 0; q < 4; q++) {
                f32x4 xv = *(const f32x4*)&x[((size_t)((b * Gg + gg) * Nn + n0)) * Tt + t0 + 4 * q];
                #pragma unroll
                for (int e = 0; e < 4; e++) {
                    int row = (q * 4 + e) * Gg + gg;
                    As[row * LDA + as_col(row, n0)] = (bf16_t)xv[e];
                }
            }
        }
    }
    __syncthreads();   // As + biases + st ready

    const float ai = aip[0], am = amp[0], ao = aop[0];

    // ---- per-wave: load own 16 As rows as GEMM1-swapped B-operand fragments
    const int row = w * 16 + l15;
    bf16x8 asf[4];
    #pragma unroll
    for (int kn = 0; kn < 4; kn++)
        asf[kn] = *(const bf16x8*)&As[row * LDA + as_col(row, kn * 32 + l4 * 8)];

    // ---- fused loop: GEMM1-swapped -> prelu -> mean(Sm) -> shuffle-redistribute -> GEMM4
    f32x4 acc4[8];
    #pragma unroll
    for (int nf = 0; nf < 8; nf++) acc4[nf] = f32x4{0.f, 0.f, 0.f, 0.f};

    const bf16_t* wiL = WiB + (size_t)l15 * Nn + l4 * 8;      // + hf*16*Nn + kn*32
    const bf16_t* woL = WoB + (size_t)l15 * 768 + l4 * 8;     // + nf*16*768 + kk*32

    #pragma unroll 2
    for (int kk = 0; kk < 12; kk++) {
        // GEMM1-swapped: D'[h][row], h-frags hf0=2kk, hf1=2kk+1; K = n = 128
        f32x4 c0 = f32x4{0.f, 0.f, 0.f, 0.f};
        f32x4 c1 = f32x4{0.f, 0.f, 0.f, 0.f};
        #pragma unroll
        for (int kn = 0; kn < 4; kn++) {
            bf16x8 w0 = *(const bf16x8*)&wiL[(size_t)(2 * kk) * 16 * Nn + kn * 32];
            bf16x8 w1 = *(const bf16x8*)&wiL[(size_t)(2 * kk + 1) * 16 * Nn + kn * 32];
            c0 = MFMA16(w0, asf[kn], c0);
            c1 = MFMA16(w1, asf[kn], c1);
        }
        // bias + prelu (lane holds Gi[row=l15-of-wave][h = hf*16 + l4*4 + j])
        f32x4 bv0 = *(const f32x4*)&sbi[(2 * kk) * 16 + l4 * 4];
        f32x4 bv1 = *(const f32x4*)&sbi[(2 * kk + 1) * 16 + l4 * 4];
        float u[4], v[4];
        #pragma unroll
        for (int j = 0; j < 4; j++) {
            float a = c0[j] + bv0[j]; u[j] = a >= 0.f ? a : ai * a;
            float bq = c1[j] + bv1[j]; v[j] = bq >= 0.f ? bq : ai * bq;
        }
        // group mean over g = lanes l15 within {0..7} / {8..15}
        float su[4], sv[4];
        #pragma unroll
        for (int j = 0; j < 4; j++) {
            float s = u[j];
            s += __shfl_xor(s, 1, 64); s += __shfl_xor(s, 2, 64); s += __shfl_xor(s, 4, 64);
            su[j] = s;
            float t = v[j];
            t += __shfl_xor(t, 1, 64); t += __shfl_xor(t, 2, 64); t += __shfl_xor(t, 4, 64);
            sv[j] = t;
        }
        if ((lane & 7) == 0) {
            int tl = 2 * w + (l15 >> 3);
            bf16x4 m0, m1;
            #pragma unroll
            for (int j = 0; j < 4; j++) {
                m0[j] = (bf16_t)(0.125f * su[j]);
                m1[j] = (bf16_t)(0.125f * sv[j]);
            }
            *(bf16x4*)&Sm[tl * LDSM + (2 * kk) * 16 + l4 * 4] = m0;
            *(bf16x4*)&Sm[tl * LDSM + (2 * kk + 1) * 16 + l4 * 4] = m1;
        }
        // pack to bf16 and redistribute across l4 so lane holds Gi[row][kk*32 + l4*8 + e]
        unsigned int P0 = pk2(u[0], u[1]), P1 = pk2(u[2], u[3]);
        unsigned int Q0 = pk2(v[0], v[1]), Q1 = pk2(v[2], v[3]);
        unsigned int rP0 = __shfl_xor((int)P0, 16, 64), rP1 = __shfl_xor((int)P1, 16, 64);
        unsigned int rQ0 = __shfl_xor((int)Q0, 16, 64), rQ1 = __shfl_xor((int)Q1, 16, 64);
        const bool odd = (l4 & 1);
        unsigned int PP0 = odd ? rP0 : P0, PP1 = odd ? rP1 : P1;
        unsigned int PP2 = odd ? P0 : rP0, PP3 = odd ? P1 : rP1;
        unsigned int QQ0 = odd ? rQ0 : Q0, QQ1 = odd ? rQ1 : Q1;
        unsigned int QQ2 = odd ? Q0 : rQ0, QQ3 = odd ? Q1 : rQ1;
        const bool hi2 = (l4 & 2);
        unsigned int V0 = hi2 ? PP0 : QQ0, V1 = hi2 ? PP1 : QQ1;
        unsigned int V2 = hi2 ? PP2 : QQ2, V3 = hi2 ? PP3 : QQ3;
        unsigned int R0 = __shfl_xor((int)V0, 32, 64), R1 = __shfl_xor((int)V1, 32, 64);
        unsigned int R2 = __shfl_xor((int)V2, 32, 64), R3 = __shfl_xor((int)V3, 32, 64);
        const bool mid = (l4 == 1) || (l4 == 2);
        u32x4 afd;
        afd[0] = mid ? R0 : (hi2 ? QQ0 : PP0);
        afd[1] = mid ? R1 : (hi2 ? QQ1 : PP1);
        afd[2] = mid ? R2 : (hi2 ? QQ2 : PP2);
        afd[3] = mid ? R3 : (hi2 ? QQ3 : PP3);
        bf16x8 af = __builtin_bit_cast(bf16x8, afd);
        // GEMM4 partial: acc4[nf] += af x Wo1-frag(kk)
        #pragma unroll
        for (int nf = 0; nf < 8; nf++) {
            bf16x8 bw = *(const bf16x8*)&woL[(size_t)nf * 16 * 768 + kk * 32];
            acc4[nf] = MFMA16(af, bw, acc4[nf]);
        }
    }
    __syncthreads();   // Sm complete (As dead: all asf loads done pre-loop)

    // ---- GEMM2: Mm[16][384] = prelu(Sm @ WmB^T + bm), K=384
    {
        const int cb2 = w * 48;
        f32x4 acc2[3];
        #pragma unroll
        for (int nc = 0; nc < 3; nc++) acc2[nc] = f32x4{0.f, 0.f, 0.f, 0.f};
        #pragma unroll
        for (int kk = 0; kk < 12; kk++) {
            const int k0 = kk * 32 + l4 * 8;
            bf16x8 a = *(const bf16x8*)&Sm[l15 * LDSM + k0];
            #pragma unroll
            for (int nc = 0; nc < 3; nc++) {
                bf16x8 bb = *(const bf16x8*)&WmB[(size_t)(cb2 + nc * 16 + l15) * Hh + k0];
                acc2[nc] = MFMA16(a, bb, acc2[nc]);
            }
        }
        #pragma unroll
        for (int nc = 0; nc < 3; nc++) {
            int col = cb2 + nc * 16 + l15;
            float bv = sbm[col];
            #pragma unroll
            for (int j = 0; j < 4; j++) {
                float vv = acc2[nc][j] + bv;
                vv = vv >= 0.f ? vv : am * vv;
                Mm[(l4 * 4 + j) * LDSM + col] = (bf16_t)vv;
            }
        }
    }
    __syncthreads();   // Mm ready

    // ---- GEMM3: Vv[16][128] = Mm @ Wo2^T, K=384
    {
        const int nblk = w * 16;
        f32x4 acc3 = f32x4{0.f, 0.f, 0.f, 0.f};
        #pragma unroll
        for (int kk = 0; kk < 12; kk++) {
            const int k0 = kk * 32 + l4 * 8;
            bf16x8 a = *(const bf16x8*)&Mm[l15 * LDSM + k0];
            bf16x8 bb = *(const bf16x8*)&WoB[(size_t)(nblk + l15) * 768 + 384 + k0];
            acc3 = MFMA16(a, bb, acc3);
        }
        #pragma unroll
        for (int j = 0; j < 4; j++) Vv[(l4 * 4 + j) * LDV + nblk + l15] = acc3[j];
    }
    __syncthreads();   // Vv ready

    // ---- epilogue: go = prelu(acc4 + Vv + bo); LN partials -> st -> part
    {
        float gsum[4] = {0.f, 0.f, 0.f, 0.f};
        float gss[4]  = {0.f, 0.f, 0.f, 0.f};
        #pragma unroll
        for (int nf = 0; nf < 8; nf++) {
            int col = nf * 16 + l15;
            float bv = sbo[col];
            #pragma unroll
            for (int j = 0; j < 4; j++) {
                int rl = l4 * 4 + j;                 // local row 0..15
                int tl = 2 * w + (rl >> 3);
                int g = rl & 7;
                float vv = acc4[nf][j] + Vv[tl * LDV + col] + bv;
                vv = vv >= 0.f ? vv : ao * vv;
                go[((size_t)((b * Tt + t0 + tl) * Gg + g)) * Nn + col] = (bf16_t)vv;
                gsum[j] += vv;
                gss[j] += vv * vv;
            }
        }
        #pragma unroll
        for (int j = 0; j < 4; j++) {
            float s = gsum[j], q = gss[j];
            #pragma unroll
            for (int off = 1; off < 16; off <<= 1) {
                s += __shfl_xor(s, off, 64);
                q += __shfl_xor(q, off, 64);
            }
            s += __shfl_xor(s, 32, 64);   // combine rows rl and rl^8 (same g, both tl)
            q += __shfl_xor(q, 32, 64);
            if (l15 == 0 && l4 < 2) {
                int g = l4 * 4 + j;
                atomicAdd(&st[g * 2 + 0], s);
                atomicAdd(&st[g * 2 + 1], q);
            }
        }
    }
    __syncthreads();
    if (tid < 16) part[(size_t)tile * 16 + tid] = st[tid];
}

// reduce part[1500][16] -> mr[32][2] (mean, rstd per (b,g))
__global__ __launch_bounds__(1024)
void k_final(const float* __restrict__ part, float* __restrict__ mr) {
    __shared__ float red[64][16];
    __shared__ float tot[4][16];
    const int tid = threadIdx.x;
    const int col = tid & 15, rb = tid >> 4;     // rb 0..63
    float s[4] = {0.f, 0.f, 0.f, 0.f};
    for (int k = 0; k < 24; k++) {
        int row = rb + (k << 6);
        if (row < NTILES) s[row / NTPB] += part[(size_t)row * 16 + col];
    }
    for (int b2 = 0; b2 < 4; b2++) {
        red[rb][col] = s[b2];
        __syncthreads();
        if (tid < 16) {
            float t = 0.f;
            #pragma unroll 8
            for (int r = 0; r < 64; r++) t += red[r][tid];
            tot[b2][tid] = t;
        }
        __syncthreads();
    }
    if (tid < 32) {
        int b2 = tid >> 3, g2 = tid & 7;
        float s0 = tot[b2][g2 * 2], s1 = tot[b2][g2 * 2 + 1];
        const float cntf = (float)Nn * (float)Tt;  // 768000
        float mean = s0 / cntf;
        float var = s1 / cntf - mean * mean;
        mr[tid * 2] = mean;
        mr[tid * 2 + 1] = rsqrtf(var + 1e-8f);
    }
}

__global__ __launch_bounds__(256)
void k_apply(const float* __restrict__ x, const bf16_t* __restrict__ go,
             const float* __restrict__ mr, const float* __restrict__ gamma,
             const float* __restrict__ beta, float* __restrict__ out) {
    __shared__ float tr[32][65];
    int bid = blockIdx.x;
    const int tt = bid % 94; bid /= 94;
    const int nn = bid & 3;  bid >>= 2;
    const int g = bid & 7;
    const int b = bid >> 3;
    const int t0 = tt * 64, n0 = nn * 32;
    const int tid = threadIdx.x;
    const float mean = mr[(b * 8 + g) * 2], rstd = mr[(b * 8 + g) * 2 + 1];

    for (int idx = tid; idx < 2048; idx += 256) {
        int nl = idx & 31, tl = idx >> 5;
        int t = t0 + tl;
        float v = 0.f;
        if (t < Tt) v = (float)go[((size_t)((b * Tt + t) * Gg + g)) * Nn + n0 + nl];
        tr[nl][tl] = v;
    }
    __syncthreads();
    for (int idx = tid; idx < 2048; idx += 256) {
        int tl = idx & 63, nl = idx >> 6;
        int t = t0 + tl;
        if (t < Tt) {
            int n = n0 + nl;
            size_t a = ((size_t)((b * Gg + g) * Nn + n)) * Tt + t;
            out[a] = x[a] + gamma[n] * (tr[nl][tl] - mean) * rstd + beta[n];
        }
    }
}

extern "C" void kernel_launch(void* const* d_in, const int* in_sizes, int n_in,
                              void* d_out, int out_size, void* d_ws, size_t ws_size,
                              hipStream_t stream) {
    const float* x     = (const float*)d_in[0];
    const float* Wi    = (const float*)d_in[1];
    const float* bi    = (const float*)d_in[2];
    const float* ai    = (const float*)d_in[3];
    const float* Wm    = (const float*)d_in[4];
    const float* bm    = (const float*)d_in[5];
    const float* am    = (const float*)d_in[6];
    const float* Wo    = (const float*)d_in[7];
    const float* bo    = (const float*)d_in[8];
    const float* ao    = (const float*)d_in[9];
    const float* gamma = (const float*)d_in[10];
    const float* beta  = (const float*)d_in[11];
    float* out = (float*)d_out;
    char* ws = (char*)d_ws;

    if (ws_size < WS_NEED) return;  // ~51.2 MB scratch required

    bf16_t* WiB = (bf16_t*)(ws + OFF_WI);
    bf16_t* WmB = (bf16_t*)(ws + OFF_WM);
    bf16_t* WoB = (bf16_t*)(ws + OFF_WO);
    float*  prt = (float*)(ws + OFF_PT);
    float*  mrs = (float*)(ws + OFF_MRS);
    bf16_t* goB = (bf16_t*)(ws + OFF_GO);

    k0_prep<<<dim3(512), dim3(256), 0, stream>>>(Wi, Wm, Wo, WiB, WmB, WoB);
    k1_fused<<<dim3(NTILES), dim3(512), 0, stream>>>(
        x, WiB, bi, ai, WmB, bm, am, WoB, bo, ao, goB, prt);
    k_final<<<dim3(1), dim3(1024), 0, stream>>>(prt, mrs);
    k_apply<<<dim3(Bq * Gg * 4 * 94), dim3(256), 0, stream>>>(x, goB, mrs, gamma, beta, out);
}

// Round 10
// 293.767 us; speedup vs baseline: 1.3817x; 1.3817x over previous
//
#include <hip/hip_runtime.h>

typedef __bf16 bf16_t;
typedef __bf16 bf16x8 __attribute__((ext_vector_type(8)));
typedef float f32x4 __attribute__((ext_vector_type(4)));

static constexpr int Bq = 4, Gg = 8, Nn = 128, Tt = 6000, Hh = 384;
static constexpr int TB = 16;              // t-values per tile
static constexpr int NTPB = Tt / TB;       // 375 tiles per batch
static constexpr int NTILES = Bq * NTPB;   // 1500 tiles (128 rows each)
static constexpr int LDA = 136;            // As row stride (bf16): 68 words, %32=4
static constexpr int LDG = 392;            // Gi row stride: 196 words, %32=4
static constexpr int LDSM = 392;           // Sm/Mm row stride
static constexpr int LDV = 132;            // Vv row stride (f32): %32=4

// workspace layout (bytes)
static constexpr size_t OFF_WI  = 0;                                    // 384x128 bf16
static constexpr size_t OFF_WM  = OFF_WI + (size_t)Hh * Nn * 2;         // 384x384 bf16
static constexpr size_t OFF_WO  = OFF_WM + (size_t)Hh * Hh * 2;         // 128x768 bf16
static constexpr size_t OFF_PT  = OFF_WO + (size_t)Nn * 2 * Hh * 2;     // part[12000][16] f32
static constexpr size_t OFF_MRS = OFF_PT + (size_t)NTILES * 8 * 16 * 4; // 32x2 f32
static constexpr size_t OFF_GO  = (size_t)2 << 20;                      // go bf16
static constexpr size_t WS_NEED = OFF_GO + (size_t)Bq * Tt * Gg * Nn * 2; // ~51.2 MB

// k1 LDS layout (bytes). As dead after GEMM1 -> Mm/Vv reuse its region.
static constexpr int SM_GI = 0;                    // Gi [128][392] bf16 = 100352
static constexpr int SM_SM = 100352;               // Sm [16][392] bf16 = 12544 -> 112896
static constexpr int SM_AS = 112896;               // As [128][136] bf16 = 34816 -> 147712
static constexpr int SM_MM = 112896;               // Mm [16][392] bf16 (reuses As)
static constexpr int SM_VV = 112896 + 12544;       // Vv [16][132] f32 = 8448 (reuses As)
static constexpr int SM_BI = 147712;               // bi f32[384] -> 149248
static constexpr int SM_BM = 149248;               // bm f32[384] -> 150784
static constexpr int SM_BO = 150784;               // bo f32[128] -> 151296
static constexpr int SMEM_BYTES = 151296;          // 1 block/CU, 8 waves

#define MFMA16(a, b, c) __builtin_amdgcn_mfma_f32_16x16x32_bf16((a), (b), (c), 0, 0, 0)

__global__ void k0_prep(const float* __restrict__ Wi, const float* __restrict__ Wm,
                        const float* __restrict__ Wo,
                        bf16_t* __restrict__ WiB, bf16_t* __restrict__ WmB,
                        bf16_t* __restrict__ WoB) {
    int i = blockIdx.x * blockDim.x + threadIdx.x;
    const int n1 = Hh * Nn, n2 = Hh * Hh, n3 = Nn * 2 * Hh;
    for (int idx = i; idx < n1 + n2 + n3; idx += gridDim.x * blockDim.x) {
        if (idx < n1)            WiB[idx] = (bf16_t)Wi[idx];
        else if (idx < n1 + n2)  WmB[idx - n1] = (bf16_t)Wm[idx - n1];
        else                     WoB[idx - n1 - n2] = (bf16_t)Wo[idx - n1 - n2];
    }
}

// As column swizzle at 16B granularity: granule (c>>3) XOR tl, tl=(row>>3)&7.
// Applied on both write and read side (involution).
__device__ __forceinline__ int as_col(int row, int c) {
    return ((((c >> 3) ^ ((row >> 3) & 7)) << 3) | (c & 7));
}

__global__ __launch_bounds__(512, 1)
void k1_fused(const float* __restrict__ x,
              const bf16_t* __restrict__ WiB, const float* __restrict__ bi, const float* __restrict__ aip,
              const bf16_t* __restrict__ WmB, const float* __restrict__ bm, const float* __restrict__ amp,
              const bf16_t* __restrict__ WoB, const float* __restrict__ bo, const float* __restrict__ aop,
              bf16_t* __restrict__ go, float* __restrict__ part) {
    __shared__ char smem[SMEM_BYTES];
    bf16_t* Gi  = (bf16_t*)(smem + SM_GI);
    bf16_t* Sm  = (bf16_t*)(smem + SM_SM);
    bf16_t* As  = (bf16_t*)(smem + SM_AS);
    bf16_t* Mm  = (bf16_t*)(smem + SM_MM);
    float*  Vv  = (float*)(smem + SM_VV);
    float*  sbi = (float*)(smem + SM_BI);
    float*  sbm = (float*)(smem + SM_BM);
    float*  sbo = (float*)(smem + SM_BO);

    const int tid  = threadIdx.x;
    const int lane = tid & 63;
    const int w    = tid >> 6;       // wave 0..7
    const int l15  = lane & 15;
    const int l4   = lane >> 4;      // 0..3
    const int tile = blockIdx.x;
    const int b    = tile / NTPB, t0 = (tile % NTPB) * TB;

    // ---- stage biases
    if (tid < 384) { sbi[tid] = bi[tid]; sbm[tid] = bm[tid]; }
    if (tid >= 384 && tid < 512) sbo[tid - 384] = bo[tid - 384];

    // ---- stage x[b, g, n, t0:t0+16] -> As[tl*8+g][swz(n)], vectorized
    {
        const int g0 = tid >> 7, n0 = tid & 127;
        #pragma unroll
        for (int h = 0; h < 2; h++) {
            int gg = g0 + 4 * h;
            #pragma unroll
            for (int q = 0; q < 4; q++) {
                f32x4 xv = *(const f32x4*)&x[((size_t)((b * Gg + gg) * Nn + n0)) * Tt + t0 + 4 * q];
                #pragma unroll
                for (int e = 0; e < 4; e++) {
                    int row = (q * 4 + e) * Gg + gg;
                    As[row * LDA + as_col(row, n0)] = (bf16_t)xv[e];
                }
            }
        }
    }

    // ---- prefetch GEMM1's first B-fragments (kk=0) above the staging barrier
    const int cb = w * 48;
    bf16x8 pre1[3];
    #pragma unroll
    for (int nc = 0; nc < 3; nc++)
        pre1[nc] = *(const bf16x8*)&WiB[(cb + nc * 16 + l15) * Nn + l4 * 8];

    __syncthreads();   // As + biases ready

    const float ai = aip[0], am = amp[0], ao = aop[0];

    // ---- GEMM1: Gi[128][384] = prelu(As @ WiB^T + bi), K=128
    // wave = 48-col slice x all 128 rows; in-register group mean -> Sm
    {
        f32x4 acc[8][3];
        #pragma unroll
        for (int mt = 0; mt < 8; mt++)
            #pragma unroll
            for (int nc = 0; nc < 3; nc++) acc[mt][nc] = f32x4{0.f, 0.f, 0.f, 0.f};
        #pragma unroll
        for (int kk = 0; kk < 4; kk++) {
            const int k0 = kk * 32 + l4 * 8;
            bf16x8 bb[3];
            #pragma unroll
            for (int nc = 0; nc < 3; nc++)
                bb[nc] = (kk == 0) ? pre1[nc]
                       : *(const bf16x8*)&WiB[(cb + nc * 16 + l15) * Nn + k0];
            #pragma unroll
            for (int mt = 0; mt < 8; mt++) {
                int row = mt * 16 + l15;
                bf16x8 a = *(const bf16x8*)&As[row * LDA + as_col(row, k0)];
                #pragma unroll
                for (int nc = 0; nc < 3; nc++) acc[mt][nc] = MFMA16(a, bb[nc], acc[mt][nc]);
            }
        }
        #pragma unroll
        for (int nc = 0; nc < 3; nc++) {
            int col = cb + nc * 16 + l15;
            float bv = sbi[col];
            #pragma unroll
            for (int mt = 0; mt < 8; mt++) {
                float ms = 0.f;
                #pragma unroll
                for (int j = 0; j < 4; j++) {
                    int row = mt * 16 + l4 * 4 + j;
                    float v = acc[mt][nc][j] + bv;
                    v = v >= 0.f ? v : ai * v;
                    Gi[row * LDG + col] = (bf16_t)v;
                    ms += v;
                }
                ms += __shfl_xor(ms, 16, 64);   // l4 0<->1, 2<->3: all 8 g's
                if ((l4 & 1) == 0) {
                    int tl = mt * 2 + (l4 >> 1);
                    Sm[tl * LDSM + col] = (bf16_t)(0.125f * ms);
                }
            }
        }
    }

    // ---- prefetch GEMM2's first B-fragments above the Gi/Sm barrier
    bf16x8 pre2[3];
    #pragma unroll
    for (int nc = 0; nc < 3; nc++)
        pre2[nc] = *(const bf16x8*)&WmB[(size_t)(cb + nc * 16 + l15) * Hh + l4 * 8];

    __syncthreads();   // Gi + Sm ready (As dead)

    // ---- GEMM2: Mm[16][384] = prelu(Sm @ WmB^T + bm), K=384
    {
        f32x4 acc2[3];
        #pragma unroll
        for (int nc = 0; nc < 3; nc++) acc2[nc] = f32x4{0.f, 0.f, 0.f, 0.f};
        #pragma unroll
        for (int kk = 0; kk < 12; kk++) {
            const int k0 = kk * 32 + l4 * 8;
            bf16x8 a = *(const bf16x8*)&Sm[l15 * LDSM + k0];
            #pragma unroll
            for (int nc = 0; nc < 3; nc++) {
                bf16x8 bb = (kk == 0) ? pre2[nc]
                          : *(const bf16x8*)&WmB[(size_t)(cb + nc * 16 + l15) * Hh + k0];
                acc2[nc] = MFMA16(a, bb, acc2[nc]);
            }
        }
        #pragma unroll
        for (int nc = 0; nc < 3; nc++) {
            int col = cb + nc * 16 + l15;
            float bv = sbm[col];
            #pragma unroll
            for (int j = 0; j < 4; j++) {
                float v = acc2[nc][j] + bv;
                v = v >= 0.f ? v : am * v;
                Mm[(l4 * 4 + j) * LDSM + col] = (bf16_t)v;
            }
        }
    }

    // ---- prefetch GEMM3's and GEMM4's first B-fragments above the Mm barrier
    const int nblk = w * 16;
    const int mh = w >> 2, ws4 = w & 3;
    const int cb4 = ws4 * 32;
    bf16x8 pre3  = *(const bf16x8*)&WoB[(size_t)(nblk + l15) * 768 + 384 + l4 * 8];
    bf16x8 pre4a = *(const bf16x8*)&WoB[(size_t)(cb4 + l15) * 768 + l4 * 8];
    bf16x8 pre4b = *(const bf16x8*)&WoB[(size_t)(cb4 + 16 + l15) * 768 + l4 * 8];

    __syncthreads();   // Mm ready

    // ---- GEMM3: Vv[16][128] = Mm @ Wo2^T, K=384  (GEMM4 main covers the stall)
    {
        f32x4 acc3 = f32x4{0.f, 0.f, 0.f, 0.f};
        #pragma unroll
        for (int kk = 0; kk < 12; kk++) {
            const int k0 = kk * 32 + l4 * 8;
            bf16x8 a = *(const bf16x8*)&Mm[l15 * LDSM + k0];
            bf16x8 bb = (kk == 0) ? pre3
                      : *(const bf16x8*)&WoB[(size_t)(nblk + l15) * 768 + 384 + k0];
            acc3 = MFMA16(a, bb, acc3);
        }
        #pragma unroll
        for (int j = 0; j < 4; j++) Vv[(l4 * 4 + j) * LDV + nblk + l15] = acc3[j];
    }

    // ---- GEMM4 main: acc = Gi @ Wo1^T, K=384 (reads only Gi; overlaps Vv latency)
    f32x4 acc4[4][2];
    #pragma unroll
    for (int mt = 0; mt < 4; mt++)
        #pragma unroll
        for (int nc = 0; nc < 2; nc++) acc4[mt][nc] = f32x4{0.f, 0.f, 0.f, 0.f};
    #pragma unroll
    for (int kk = 0; kk < 12; kk++) {
        const int k0 = kk * 32 + l4 * 8;
        bf16x8 b0 = (kk == 0) ? pre4a : *(const bf16x8*)&WoB[(size_t)(cb4 + l15) * 768 + k0];
        bf16x8 b1 = (kk == 0) ? pre4b : *(const bf16x8*)&WoB[(size_t)(cb4 + 16 + l15) * 768 + k0];
        bf16x8 a[4];
        #pragma unroll
        for (int mt = 0; mt < 4; mt++)
            a[mt] = *(const bf16x8*)&Gi[(mh * 64 + mt * 16 + l15) * LDG + k0];
        #pragma unroll
        for (int mt = 0; mt < 4; mt++) {
            acc4[mt][0] = MFMA16(a[mt], b0, acc4[mt][0]);
            acc4[mt][1] = MFMA16(a[mt], b1, acc4[mt][1]);
        }
    }
    __syncthreads();   // Vv ready

    // ---- epilogue: go = prelu(acc4 + Vv + bo); per-wave LN partials -> part
    {
        float gsum[4] = {0.f, 0.f, 0.f, 0.f};
        float gss[4]  = {0.f, 0.f, 0.f, 0.f};
        #pragma unroll
        for (int nc = 0; nc < 2; nc++) {
            int col = cb4 + nc * 16 + l15;
            float bv = sbo[col];
            #pragma unroll
            for (int mt = 0; mt < 4; mt++) {
                #pragma unroll
                for (int j = 0; j < 4; j++) {
                    int row = mh * 64 + mt * 16 + l4 * 4 + j;
                    int tl = row >> 3;
                    int g = row & 7;
                    float v = acc4[mt][nc][j] + Vv[tl * LDV + col] + bv;
                    v = v >= 0.f ? v : ao * v;
                    go[((size_t)((b * Tt + t0 + tl) * Gg + g)) * Nn + col] = (bf16_t)v;
                    gsum[j] += v;
                    gss[j] += v * v;
                }
            }
        }
        #pragma unroll
        for (int j = 0; j < 4; j++) {
            float s = gsum[j], q = gss[j];
            #pragma unroll
            for (int off = 1; off < 16; off <<= 1) {
                s += __shfl_xor(s, off, 64);
                q += __shfl_xor(q, off, 64);
            }
            s += __shfl_xor(s, 32, 64);   // l4 0<->2, 1<->3 (same g, other tl half)
            q += __shfl_xor(q, 32, 64);
            if (l15 == 0 && l4 < 2) {
                int g = l4 * 4 + j;
                part[((size_t)tile * 8 + w) * 16 + g * 2 + 0] = s;
                part[((size_t)tile * 8 + w) * 16 + g * 2 + 1] = q;
            }
        }
    }
}

// reduce part[12000][16] -> mr[32][2] (mean, rstd per (b,g))
__global__ __launch_bounds__(1024)
void k_final(const float* __restrict__ part, float* __restrict__ mr) {
    __shared__ float red[64][16];
    __shared__ float tot[4][16];
    const int tid = threadIdx.x;
    const int col = tid & 15, rb = tid >> 4;     // rb 0..63
    const int R = NTILES * 8;                    // 12000
    const int rowsPerB = R / Bq;                 // 3000
    float s[4] = {0.f, 0.f, 0.f, 0.f};
    for (int row = rb; row < R; row += 64)
        s[row / rowsPerB] += part[(size_t)row * 16 + col];
    for (int b2 = 0; b2 < 4; b2++) {
        red[rb][col] = s[b2];
        __syncthreads();
        if (tid < 16) {
            float t = 0.f;
            #pragma unroll 8
            for (int r = 0; r < 64; r++) t += red[r][tid];
            tot[b2][tid] = t;
        }
        __syncthreads();
    }
    if (tid < 32) {
        int b2 = tid >> 3, g2 = tid & 7;
        float s0 = tot[b2][g2 * 2], s1 = tot[b2][g2 * 2 + 1];
        const float cntf = (float)Nn * (float)Tt;  // 768000
        float mean = s0 / cntf;
        float var = s1 / cntf - mean * mean;
        mr[tid * 2] = mean;
        mr[tid * 2 + 1] = rsqrtf(var + 1e-8f);
    }
}

__global__ __launch_bounds__(256)
void k_apply(const float* __restrict__ x, const bf16_t* __restrict__ go,
             const float* __restrict__ mr, const float* __restrict__ gamma,
             const float* __restrict__ beta, float* __restrict__ out) {
    __shared__ float tr[32][65];
    int bid = blockIdx.x;
    const int tt = bid % 94; bid /= 94;
    const int nn = bid & 3;  bid >>= 2;
    const int g = bid & 7;
    const int b = bid >> 3;
    const int t0 = tt * 64, n0 = nn * 32;
    const int tid = threadIdx.x;
    const float mean = mr[(b * 8 + g) * 2], rstd = mr[(b * 8 + g) * 2 + 1];

    for (int idx = tid; idx < 2048; idx += 256) {
        int nl = idx & 31, tl = idx >> 5;
        int t = t0 + tl;
        float v = 0.f;
        if (t < Tt) v = (float)go[((size_t)((b * Tt + t) * Gg + g)) * Nn + n0 + nl];
        tr[nl][tl] = v;
    }
    __syncthreads();
    for (int idx = tid; idx < 2048; idx += 256) {
        int tl = idx & 63, nl = idx >> 6;
        int t = t0 + tl;
        if (t < Tt) {
            int n = n0 + nl;
            size_t a = ((size_t)((b * Gg + g) * Nn + n)) * Tt + t;
            out[a] = x[a] + gamma[n] * (tr[nl][tl] - mean) * rstd + beta[n];
        }
    }
}

extern "C" void kernel_launch(void* const* d_in, const int* in_sizes, int n_in,
                              void* d_out, int out_size, void* d_ws, size_t ws_size,
                              hipStream_t stream) {
    const float* x     = (const float*)d_in[0];
    const float* Wi    = (const float*)d_in[1];
    const float* bi    = (const float*)d_in[2];
    const float* ai    = (const float*)d_in[3];
    const float* Wm    = (const float*)d_in[4];
    const float* bm    = (const float*)d_in[5];
    const float* am    = (const float*)d_in[6];
    const float* Wo    = (const float*)d_in[7];
    const float* bo    = (const float*)d_in[8];
    const float* ao    = (const float*)d_in[9];
    const float* gamma = (const float*)d_in[10];
    const float* beta  = (const float*)d_in[11];
    float* out = (float*)d_out;
    char* ws = (char*)d_ws;

    if (ws_size < WS_NEED) return;  // ~51.2 MB scratch required

    bf16_t* WiB = (bf16_t*)(ws + OFF_WI);
    bf16_t* WmB = (bf16_t*)(ws + OFF_WM);
    bf16_t* WoB = (bf16_t*)(ws + OFF_WO);
    float*  prt = (float*)(ws + OFF_PT);
    float*  mrs = (float*)(ws + OFF_MRS);
    bf16_t* goB = (bf16_t*)(ws + OFF_GO);

    k0_prep<<<dim3(512), dim3(256), 0, stream>>>(Wi, Wm, Wo, WiB, WmB, WoB);
    k1_fused<<<dim3(NTILES), dim3(512), 0, stream>>>(
        x, WiB, bi, ai, WmB, bm, am, WoB, bo, ao, goB, prt);
    k_final<<<dim3(1), dim3(1024), 0, stream>>>(prt, mrs);
    k_apply<<<dim3(Bq * Gg * 4 * 94), dim3(256), 0, stream>>>(x, goB, mrs, gamma, beta, out);
}